// Round 1
// baseline (572.146 us; speedup 1.0000x reference)
//
#include <hip/hip_runtime.h>
#include <hip/hip_bf16.h>

#define HW 16384
#define NPIX 65536
#define CC 256
#define NDIL 16
#define DFF 8
#define CATC 384
#define LNEPS 1e-3f

typedef short bf16x8 __attribute__((ext_vector_type(8)));
typedef float f32x4 __attribute__((ext_vector_type(4)));

__device__ __forceinline__ unsigned short f2bf(float f) {
    unsigned u = __builtin_bit_cast(unsigned, f);
    u += 0x7fffu + ((u >> 16) & 1u);
    return (unsigned short)(u >> 16);
}

// ---------------- prep: repack dwn weights + smooth weights(bf16, [tap][co][ci]) ----
__global__ void prep_kernel(const float* __restrict__ dwn_w,
                            const float* __restrict__ smooth_w,
                            float* __restrict__ W2, unsigned short* __restrict__ Wbf) {
    int idx = blockIdx.x * 256 + threadIdx.x;
    if (idx < 256 * 128) {
        int c = idx >> 7, j = idx & 127;
        int i = j >> 3, f = j & 7;
        W2[idx] = dwn_w[(i * 256 + c) * 8 + f];   // dwn_w [ND][1][1][C][DF]
    }
    int idx2 = idx - 256 * 128;
    if (idx2 >= 0 && idx2 < 9 * 256 * 384) {
        int tap = idx2 / (256 * 384);
        int rem = idx2 % (256 * 384);
        int co = rem / 384, ci = rem % 384;
        Wbf[idx2] = f2bf(smooth_w[(tap * 384 + ci) * 256 + co]); // smooth_w [3][3][CAT][C]
    }
}

// ---------------- K1: input LN, writes fp32 xn and bf16 cat[:,0:256] ----------------
__global__ void ln_in_kernel(const float* __restrict__ x, const float* __restrict__ g,
                             const float* __restrict__ b,
                             float* __restrict__ xn, unsigned short* __restrict__ cat) {
    int wid = threadIdx.x >> 6, lane = threadIdx.x & 63;
    int pix = blockIdx.x * 4 + wid;
    float4 v = ((const float4*)(x + (size_t)pix * CC))[lane];
    float s = v.x + v.y + v.z + v.w;
    float ss = v.x * v.x + v.y * v.y + v.z * v.z + v.w * v.w;
    #pragma unroll
    for (int m = 1; m < 64; m <<= 1) { s += __shfl_xor(s, m); ss += __shfl_xor(ss, m); }
    float mean = s * (1.f / 256.f);
    float rstd = rsqrtf(ss * (1.f / 256.f) - mean * mean + LNEPS);
    float4 gv = ((const float4*)g)[lane];
    float4 bv = ((const float4*)b)[lane];
    float4 y;
    y.x = (v.x - mean) * rstd * gv.x + bv.x;
    y.y = (v.y - mean) * rstd * gv.y + bv.y;
    y.z = (v.z - mean) * rstd * gv.z + bv.z;
    y.w = (v.w - mean) * rstd * gv.w + bv.w;
    ((float4*)(xn + (size_t)pix * CC))[lane] = y;
    ushort4* cp = (ushort4*)(cat + (size_t)pix * CATC + lane * 4);
    *cp = make_ushort4(f2bf(y.x), f2bf(y.y), f2bf(y.z), f2bf(y.w));
}

// ---------------- K2: fused 1x1 conv for all 16 branches (256 -> 128) ---------------
__global__ void dwn_kernel(const float* __restrict__ xn, const float* __restrict__ W2,
                           const float* __restrict__ dwn_b, float* __restrict__ dx) {
    __shared__ float xrow[16][256];
    int tid = threadIdx.x;
    int pb = blockIdx.x * 16;
    for (int it = 0; it < 16; it++)
        xrow[it][tid] = xn[(size_t)(pb + it) * CC + tid];
    __syncthreads();
    int j = tid & 127, pg = tid >> 7;
    float acc[8];
    float bias = dwn_b[j];
    #pragma unroll
    for (int p = 0; p < 8; p++) acc[p] = bias;
    for (int c4 = 0; c4 < 64; c4++) {
        float w0 = W2[(c4 * 4 + 0) * 128 + j];
        float w1 = W2[(c4 * 4 + 1) * 128 + j];
        float w2 = W2[(c4 * 4 + 2) * 128 + j];
        float w3 = W2[(c4 * 4 + 3) * 128 + j];
        #pragma unroll
        for (int p = 0; p < 8; p++) {
            float4 xv = *(const float4*)&xrow[pg * 8 + p][c4 * 4];
            acc[p] = fmaf(xv.x, w0, fmaf(xv.y, w1, fmaf(xv.z, w2, fmaf(xv.w, w3, acc[p]))));
        }
    }
    #pragma unroll
    for (int p = 0; p < 8; p++)
        dx[(size_t)(pb + pg * 8 + p) * 128 + j] = fmaxf(acc[p], 0.f);
}

// ---------------- K3: per-branch dilated 3x3 k,q,v convs; writes kq^T and v ---------
__global__ void branch_conv_kernel(const float* __restrict__ dx,
                                   const float* __restrict__ k_w, const float* __restrict__ k_b,
                                   const float* __restrict__ q_w, const float* __restrict__ q_b,
                                   const float* __restrict__ v_w, const float* __restrict__ v_b,
                                   float* __restrict__ kq_t, float* __restrict__ vbuf) {
    __shared__ float wk[576], wq[576], wv[576];
    __shared__ float bk[8], bq[8], bv[8];
    int i = blockIdx.y;
    int tid = threadIdx.x;
    for (int idx = tid; idx < 576; idx += 256) {
        wk[idx] = k_w[i * 576 + idx];
        wq[idx] = q_w[i * 576 + idx];
        wv[idx] = v_w[i * 576 + idx];
    }
    if (tid < 8) { bk[tid] = k_b[i * 8 + tid]; bq[tid] = q_b[i * 8 + tid]; bv[tid] = v_b[i * 8 + tid]; }
    __syncthreads();
    int pix = blockIdx.x * 256 + tid;
    int n = pix >> 14, hw = pix & 16383, h = hw >> 7, w = hw & 127;
    int d = i + 1;
    float k[8], q[8], v[8];
    #pragma unroll
    for (int f = 0; f < 8; f++) { k[f] = bk[f]; q[f] = bq[f]; v[f] = bv[f]; }
    #pragma unroll
    for (int ty = 0; ty < 3; ty++) {
        int sy = h + (ty - 1) * d;
        if (sy < 0 || sy >= 128) continue;
        #pragma unroll
        for (int tx = 0; tx < 3; tx++) {
            int sx = w + (tx - 1) * d;
            if (sx < 0 || sx >= 128) continue;
            const float4* src = (const float4*)(dx + (size_t)(((n << 14) + sy * 128 + sx)) * 128 + i * 8);
            float a[8];
            *(float4*)&a[0] = src[0];
            *(float4*)&a[4] = src[1];
            int wb = (ty * 3 + tx) * 64;
            #pragma unroll
            for (int ci = 0; ci < 8; ci++) {
                float xv = a[ci];
                float4 k0 = *(const float4*)&wk[wb + ci * 8];
                float4 k1 = *(const float4*)&wk[wb + ci * 8 + 4];
                float4 q0 = *(const float4*)&wq[wb + ci * 8];
                float4 q1 = *(const float4*)&wq[wb + ci * 8 + 4];
                float4 v0 = *(const float4*)&wv[wb + ci * 8];
                float4 v1 = *(const float4*)&wv[wb + ci * 8 + 4];
                k[0] = fmaf(xv, k0.x, k[0]); k[1] = fmaf(xv, k0.y, k[1]);
                k[2] = fmaf(xv, k0.z, k[2]); k[3] = fmaf(xv, k0.w, k[3]);
                k[4] = fmaf(xv, k1.x, k[4]); k[5] = fmaf(xv, k1.y, k[5]);
                k[6] = fmaf(xv, k1.z, k[6]); k[7] = fmaf(xv, k1.w, k[7]);
                q[0] = fmaf(xv, q0.x, q[0]); q[1] = fmaf(xv, q0.y, q[1]);
                q[2] = fmaf(xv, q0.z, q[2]); q[3] = fmaf(xv, q0.w, q[3]);
                q[4] = fmaf(xv, q1.x, q[4]); q[5] = fmaf(xv, q1.y, q[5]);
                q[6] = fmaf(xv, q1.z, q[6]); q[7] = fmaf(xv, q1.w, q[7]);
                v[0] = fmaf(xv, v0.x, v[0]); v[1] = fmaf(xv, v0.y, v[1]);
                v[2] = fmaf(xv, v0.z, v[2]); v[3] = fmaf(xv, v0.w, v[3]);
                v[4] = fmaf(xv, v1.x, v[4]); v[5] = fmaf(xv, v1.y, v[5]);
                v[6] = fmaf(xv, v1.z, v[6]); v[7] = fmaf(xv, v1.w, v[7]);
            }
        }
    }
    #pragma unroll
    for (int f = 0; f < 8; f++) {
        float kk = fmaxf(k[f], 0.f), qq = fmaxf(q[f], 0.f);
        kq_t[((size_t)(n * 128 + i * 8 + f) << 14) + hw] = kk * qq;
    }
    float4* vp = (float4*)(vbuf + (size_t)pix * 128 + i * 8);
    vp[0] = make_float4(fmaxf(v[0], 0.f), fmaxf(v[1], 0.f), fmaxf(v[2], 0.f), fmaxf(v[3], 0.f));
    vp[1] = make_float4(fmaxf(v[4], 0.f), fmaxf(v[5], 0.f), fmaxf(v[6], 0.f), fmaxf(v[7], 0.f));
}

// ---------------- K4: spatial softmax stats (max, sumexp) per (n, branch-chan) ------
__global__ void softmax_stats_kernel(const float* __restrict__ kq_t, float2* __restrict__ stats) {
    int r = blockIdx.x;
    const float* base = kq_t + ((size_t)r << 14);
    int tid = threadIdx.x;
    int wid = tid >> 6, lane = tid & 63;
    __shared__ float red[4], red2[4];
    float m = -1e30f;
    for (int idx = tid; idx < HW; idx += 256) m = fmaxf(m, base[idx]);
    #pragma unroll
    for (int msk = 1; msk < 64; msk <<= 1) m = fmaxf(m, __shfl_xor(m, msk));
    if (lane == 0) red[wid] = m;
    __syncthreads();
    m = fmaxf(fmaxf(red[0], red[1]), fmaxf(red[2], red[3]));
    float s = 0.f;
    for (int idx = tid; idx < HW; idx += 256) s += __expf(base[idx] - m);
    #pragma unroll
    for (int msk = 1; msk < 64; msk <<= 1) s += __shfl_xor(s, msk);
    if (lane == 0) red2[wid] = s;
    __syncthreads();
    if (tid == 0) stats[r] = make_float2(m, red2[0] + red2[1] + red2[2] + red2[3]);
}

// ---------------- K5: attn*v + LN(8) -> cat[:,256:384] bf16 -------------------------
__global__ void branch_out_kernel(const float* __restrict__ kq_t, const float* __restrict__ vbuf,
                                  const float2* __restrict__ stats,
                                  const float* __restrict__ g_up, const float* __restrict__ b_up,
                                  unsigned short* __restrict__ cat) {
    int i = blockIdx.y;
    int pix = blockIdx.x * 256 + threadIdx.x;
    int n = pix >> 14, hw = pix & 16383;
    float va[8];
    *(float4*)&va[0] = *(const float4*)(vbuf + (size_t)pix * 128 + i * 8);
    *(float4*)&va[4] = *(const float4*)(vbuf + (size_t)pix * 128 + i * 8 + 4);
    float y[8];
    float s = 0.f, ss = 0.f;
    #pragma unroll
    for (int f = 0; f < 8; f++) {
        int r = n * 128 + i * 8 + f;
        float2 st = stats[r];
        float a = __expf(kq_t[((size_t)r << 14) + hw] - st.x) / st.y;
        y[f] = a * va[f];
        s += y[f]; ss += y[f] * y[f];
    }
    float m = s * 0.125f;
    float rstd = rsqrtf(ss * 0.125f - m * m + LNEPS);
    unsigned short o[8];
    #pragma unroll
    for (int f = 0; f < 8; f++) o[f] = f2bf((y[f] - m) * rstd * g_up[f] + b_up[f]);
    ushort4* cp = (ushort4*)(cat + (size_t)pix * CATC + 256 + i * 8);
    cp[0] = make_ushort4(o[0], o[1], o[2], o[3]);
    cp[1] = make_ushort4(o[4], o[5], o[6], o[7]);
}

// ---------------- K6: smooth 3x3 conv (384->256) bf16 MFMA + ReLU + LN fused --------
__global__ __launch_bounds__(256)
void smooth_ln_kernel(const unsigned short* __restrict__ cat, const unsigned short* __restrict__ Wbf,
                      const float* __restrict__ smooth_b, const float* __restrict__ g_out,
                      const float* __restrict__ b_out, float* __restrict__ out) {
    __shared__ unsigned short Alds[64 * 40];   // 64 px  x 32 k (pad to 40)
    __shared__ unsigned short Blds[256 * 40];  // 256 co x 32 k (pad to 40)
    __shared__ float pwave[4][64][2];
    __shared__ float mrs[64][2];
    int tid = threadIdx.x;
    int wv = tid >> 6, lane = tid & 63;
    int ml = lane & 15, quad = lane >> 4;
    int pb = blockIdx.x * 64;                   // 64-pixel strip, same image row
    int n = pb >> 14, rem = pb & 16383, h0 = rem >> 7, w0 = rem & 127;

    float sbias[4], gg[4], bb[4];
    #pragma unroll
    for (int ni = 0; ni < 4; ni++) {
        int co = wv * 64 + ni * 16 + ml;
        sbias[ni] = smooth_b[co]; gg[ni] = g_out[co]; bb[ni] = b_out[co];
    }
    f32x4 acc[4][4];
    #pragma unroll
    for (int mi = 0; mi < 4; mi++)
        #pragma unroll
        for (int ni = 0; ni < 4; ni++)
            acc[mi][ni] = (f32x4){0.f, 0.f, 0.f, 0.f};

    int r = tid >> 2, sub = tid & 3;
    for (int tap = 0; tap < 9; tap++) {
        int dy = tap / 3 - 1, dxo = tap % 3 - 1;
        int srow = h0 + dy;
        int scol = w0 + r + dxo;
        bool valid = (srow >= 0) && (srow < 128) && (scol >= 0) && (scol < 128);
        const unsigned short* asrc = cat + (size_t)((n << 14) + srow * 128 + scol) * CATC;
        for (int kc = 0; kc < 12; kc++) {
            __syncthreads();
            uint4 av = make_uint4(0u, 0u, 0u, 0u);
            if (valid) av = *(const uint4*)(asrc + kc * 32 + sub * 8);
            *(uint4*)&Alds[r * 40 + sub * 8] = av;
            #pragma unroll
            for (int it = 0; it < 4; it++) {
                int idx = it * 256 + tid;
                int co = idx >> 2, bs = idx & 3;
                uint4 bvv = *(const uint4*)(Wbf + (size_t)(tap * 256 + co) * CATC + kc * 32 + bs * 8);
                *(uint4*)&Blds[co * 40 + bs * 8] = bvv;
            }
            __syncthreads();
            bf16x8 af[4], bfr[4];
            #pragma unroll
            for (int mi = 0; mi < 4; mi++)
                af[mi] = *(const bf16x8*)&Alds[(mi * 16 + ml) * 40 + quad * 8];
            #pragma unroll
            for (int ni = 0; ni < 4; ni++)
                bfr[ni] = *(const bf16x8*)&Blds[(wv * 64 + ni * 16 + ml) * 40 + quad * 8];
            #pragma unroll
            for (int mi = 0; mi < 4; mi++)
                #pragma unroll
                for (int ni = 0; ni < 4; ni++)
                    acc[mi][ni] = __builtin_amdgcn_mfma_f32_16x16x32_bf16(af[mi], bfr[ni], acc[mi][ni], 0, 0, 0);
        }
    }
    // fused bias + relu + LN(256) epilogue
    #pragma unroll
    for (int mi = 0; mi < 4; mi++) {
        #pragma unroll
        for (int rg = 0; rg < 4; rg++) {
            float s = 0.f, ss = 0.f;
            #pragma unroll
            for (int ni = 0; ni < 4; ni++) {
                float v = fmaxf(acc[mi][ni][rg] + sbias[ni], 0.f);
                s += v; ss += v * v;
            }
            #pragma unroll
            for (int msk = 1; msk < 16; msk <<= 1) { s += __shfl_xor(s, msk); ss += __shfl_xor(ss, msk); }
            if (ml == 0) {
                int P = mi * 16 + quad * 4 + rg;
                pwave[wv][P][0] = s; pwave[wv][P][1] = ss;
            }
        }
    }
    __syncthreads();
    if (tid < 64) {
        float s = pwave[0][tid][0] + pwave[1][tid][0] + pwave[2][tid][0] + pwave[3][tid][0];
        float ss = pwave[0][tid][1] + pwave[1][tid][1] + pwave[2][tid][1] + pwave[3][tid][1];
        float m = s * (1.f / 256.f);
        mrs[tid][0] = m;
        mrs[tid][1] = rsqrtf(ss * (1.f / 256.f) - m * m + LNEPS);
    }
    __syncthreads();
    #pragma unroll
    for (int mi = 0; mi < 4; mi++) {
        #pragma unroll
        for (int rg = 0; rg < 4; rg++) {
            int P = mi * 16 + quad * 4 + rg;
            float m = mrs[P][0], rs = mrs[P][1];
            #pragma unroll
            for (int ni = 0; ni < 4; ni++) {
                float v = fmaxf(acc[mi][ni][rg] + sbias[ni], 0.f);
                out[(size_t)(pb + P) * 256 + wv * 64 + ni * 16 + ml] = (v - m) * rs * gg[ni] + bb[ni];
            }
        }
    }
}

extern "C" void kernel_launch(void* const* d_in, const int* in_sizes, int n_in,
                              void* d_out, int out_size, void* d_ws, size_t ws_size,
                              hipStream_t stream) {
    const float* x        = (const float*)d_in[0];
    const float* dwn_w    = (const float*)d_in[1];
    const float* dwn_b    = (const float*)d_in[2];
    const float* k_w      = (const float*)d_in[3];
    const float* k_b      = (const float*)d_in[4];
    const float* q_w      = (const float*)d_in[5];
    const float* q_b      = (const float*)d_in[6];
    const float* v_w      = (const float*)d_in[7];
    const float* v_b      = (const float*)d_in[8];
    const float* smooth_w = (const float*)d_in[9];
    const float* smooth_b = (const float*)d_in[10];
    const float* ln_in_g  = (const float*)d_in[11];
    const float* ln_in_b  = (const float*)d_in[12];
    const float* ln_up_g  = (const float*)d_in[13];
    const float* ln_up_b  = (const float*)d_in[14];
    const float* ln_out_g = (const float*)d_in[15];
    const float* ln_out_b = (const float*)d_in[16];

    char* ws = (char*)d_ws;
    float*          xn    = (float*)(ws);                          // 64 MB
    float*          dx    = (float*)(ws + 67108864);               // 32 MB
    float*          kq_t  = (float*)(ws + 100663296);              // 32 MB
    float*          vbuf  = (float*)(ws + 134217728);              // 32 MB
    unsigned short* cat   = (unsigned short*)(ws + 167772160);     // 48 MB
    float2*         stats = (float2*)(ws + 218103808);             // 4 KB
    float*          W2    = (float*)(ws + 218107904);              // 128 KB
    unsigned short* Wbf   = (unsigned short*)(ws + 218238976);     // 1.7 MB
    float* out = (float*)d_out;

    prep_kernel<<<3584, 256, 0, stream>>>(dwn_w, smooth_w, W2, Wbf);
    ln_in_kernel<<<16384, 256, 0, stream>>>(x, ln_in_g, ln_in_b, xn, cat);
    dwn_kernel<<<4096, 256, 0, stream>>>(xn, W2, dwn_b, dx);
    branch_conv_kernel<<<dim3(256, 16), 256, 0, stream>>>(dx, k_w, k_b, q_w, q_b, v_w, v_b, kq_t, vbuf);
    softmax_stats_kernel<<<512, 256, 0, stream>>>(kq_t, stats);
    branch_out_kernel<<<dim3(256, 16), 256, 0, stream>>>(kq_t, vbuf, stats, ln_up_g, ln_up_b, cat);
    smooth_ln_kernel<<<1024, 256, 0, stream>>>(cat, Wbf, smooth_b, ln_out_g, ln_out_b, out);
}

// Round 2
// 415.460 us; speedup vs baseline: 1.3771x; 1.3771x over previous
//
#include <hip/hip_runtime.h>
#include <hip/hip_bf16.h>

#define HW 16384
#define NPIX 65536
#define CC 256
#define NDIL 16
#define DFF 8
#define CATC 384
#define LNEPS 1e-3f

typedef short bf16x8 __attribute__((ext_vector_type(8)));
typedef float f32x4 __attribute__((ext_vector_type(4)));

__device__ __forceinline__ unsigned short f2bf(float f) {
    unsigned u = __builtin_bit_cast(unsigned, f);
    u += 0x7fffu + ((u >> 16) & 1u);
    return (unsigned short)(u >> 16);
}
__device__ __forceinline__ float bf2f(unsigned short s) {
    return __builtin_bit_cast(float, (unsigned)s << 16);
}
__device__ __forceinline__ void bfpair(unsigned u, float& a, float& b) {
    a = __builtin_bit_cast(float, u << 16);
    b = __builtin_bit_cast(float, u & 0xffff0000u);
}

// -------- prep: dwn weights -> bf16 [co=128][k=256]; smooth -> bf16 [kc][tap][co][32]
__global__ void prep_kernel(const float* __restrict__ dwn_w,
                            const float* __restrict__ smooth_w,
                            unsigned short* __restrict__ Wd, unsigned short* __restrict__ Wbf) {
    int idx = blockIdx.x * 256 + threadIdx.x;
    if (idx < 128 * 256) {
        int co = idx >> 8, k = idx & 255;
        int i = co >> 3, f = co & 7;
        Wd[idx] = f2bf(dwn_w[(i * 256 + k) * 8 + f]);     // dwn_w [ND][1][1][C][DF]
    }
    int idx2 = idx - 128 * 256;
    if (idx2 >= 0 && idx2 < 12 * 9 * 256 * 32) {
        int k = idx2 & 31;
        int t = idx2 >> 5;
        int co = t & 255;
        int t2 = t >> 8;
        int tap = t2 % 9;
        int kc = t2 / 9;
        int ci = kc * 32 + k;
        Wbf[idx2] = f2bf(smooth_w[(tap * 384 + ci) * 256 + co]); // smooth_w [3][3][CAT][C]
    }
}

// -------- K1: input LN -> bf16 cat[:,0:256] ----------------------------------------
__global__ void ln_in_kernel(const float* __restrict__ x, const float* __restrict__ g,
                             const float* __restrict__ b, unsigned short* __restrict__ cat) {
    int wid = threadIdx.x >> 6, lane = threadIdx.x & 63;
    int pix = blockIdx.x * 4 + wid;
    float4 v = ((const float4*)(x + (size_t)pix * CC))[lane];
    float s = v.x + v.y + v.z + v.w;
    float ss = v.x * v.x + v.y * v.y + v.z * v.z + v.w * v.w;
    #pragma unroll
    for (int m = 1; m < 64; m <<= 1) { s += __shfl_xor(s, m); ss += __shfl_xor(ss, m); }
    float mean = s * (1.f / 256.f);
    float rstd = rsqrtf(ss * (1.f / 256.f) - mean * mean + LNEPS);
    float4 gv = ((const float4*)g)[lane];
    float4 bv = ((const float4*)b)[lane];
    float4 y;
    y.x = (v.x - mean) * rstd * gv.x + bv.x;
    y.y = (v.y - mean) * rstd * gv.y + bv.y;
    y.z = (v.z - mean) * rstd * gv.z + bv.z;
    y.w = (v.w - mean) * rstd * gv.w + bv.w;
    ushort4* cp = (ushort4*)(cat + (size_t)pix * CATC + lane * 4);
    *cp = make_ushort4(f2bf(y.x), f2bf(y.y), f2bf(y.z), f2bf(y.w));
}

// -------- K2: dwn 1x1 conv as bf16 MFMA GEMM (65536 x 256 x 128), relu, bf16 out ----
__global__ __launch_bounds__(256)
void dwn_mfma_kernel(const unsigned short* __restrict__ cat, const unsigned short* __restrict__ Wd,
                     const float* __restrict__ dwn_b, unsigned short* __restrict__ dxb) {
    __shared__ unsigned short Alds[128 * 40];
    int tid = threadIdx.x;
    int wv = tid >> 6, lane = tid & 63;
    int ml = lane & 15, quad = lane >> 4;
    int pb = blockIdx.x * 128;
    f32x4 acc[8][2];
    #pragma unroll
    for (int mi = 0; mi < 8; mi++)
        #pragma unroll
        for (int ni = 0; ni < 2; ni++) acc[mi][ni] = (f32x4){0.f, 0.f, 0.f, 0.f};

    for (int kc = 0; kc < 8; kc++) {
        __syncthreads();
        #pragma unroll
        for (int it = 0; it < 2; it++) {
            int idx = it * 256 + tid;
            int p = idx >> 2, sub = idx & 3;
            uint4 av = *(const uint4*)(cat + (size_t)(pb + p) * CATC + kc * 32 + sub * 8);
            *(uint4*)&Alds[p * 40 + sub * 8] = av;
        }
        __syncthreads();
        bf16x8 bv[2];
        #pragma unroll
        for (int ni = 0; ni < 2; ni++) {
            int co = wv * 32 + ni * 16 + ml;
            bv[ni] = *(const bf16x8*)(Wd + (size_t)co * 256 + kc * 32 + quad * 8);
        }
        bf16x8 af[8];
        #pragma unroll
        for (int mi = 0; mi < 8; mi++)
            af[mi] = *(const bf16x8*)&Alds[(mi * 16 + ml) * 40 + quad * 8];
        #pragma unroll
        for (int mi = 0; mi < 8; mi++)
            #pragma unroll
            for (int ni = 0; ni < 2; ni++)
                acc[mi][ni] = __builtin_amdgcn_mfma_f32_16x16x32_bf16(af[mi], bv[ni], acc[mi][ni], 0, 0, 0);
    }
    float bias[2];
    #pragma unroll
    for (int ni = 0; ni < 2; ni++) bias[ni] = dwn_b[wv * 32 + ni * 16 + ml];
    #pragma unroll
    for (int mi = 0; mi < 8; mi++)
        #pragma unroll
        for (int rg = 0; rg < 4; rg++) {
            int pixel = mi * 16 + quad * 4 + rg;
            #pragma unroll
            for (int ni = 0; ni < 2; ni++) {
                float v = fmaxf(acc[mi][ni][rg] + bias[ni], 0.f);
                dxb[(size_t)(pb + pixel) * 128 + wv * 32 + ni * 16 + ml] = f2bf(v);
            }
        }
}

// -------- K3: per-branch dilated 3x3 k,q,v convs (bf16 in, fp32 math) ---------------
__global__ void branch_conv_kernel(const unsigned short* __restrict__ dxb,
                                   const float* __restrict__ k_w, const float* __restrict__ k_b,
                                   const float* __restrict__ q_w, const float* __restrict__ q_b,
                                   const float* __restrict__ v_w, const float* __restrict__ v_b,
                                   float* __restrict__ kq_t, float* __restrict__ vbuf) {
    __shared__ float wk[576], wq[576], wv_[576];
    __shared__ float bk[8], bq[8], bv[8];
    int i = blockIdx.y;
    int tid = threadIdx.x;
    for (int idx = tid; idx < 576; idx += 256) {
        wk[idx] = k_w[i * 576 + idx];
        wq[idx] = q_w[i * 576 + idx];
        wv_[idx] = v_w[i * 576 + idx];
    }
    if (tid < 8) { bk[tid] = k_b[i * 8 + tid]; bq[tid] = q_b[i * 8 + tid]; bv[tid] = v_b[i * 8 + tid]; }
    __syncthreads();
    int pix = blockIdx.x * 256 + tid;
    int n = pix >> 14, hw = pix & 16383, h = hw >> 7, w = hw & 127;
    int d = i + 1;
    float k[8], q[8], v[8];
    #pragma unroll
    for (int f = 0; f < 8; f++) { k[f] = bk[f]; q[f] = bq[f]; v[f] = bv[f]; }
    #pragma unroll
    for (int ty = 0; ty < 3; ty++) {
        int sy = h + (ty - 1) * d;
        if (sy < 0 || sy >= 128) continue;
        #pragma unroll
        for (int tx = 0; tx < 3; tx++) {
            int sx = w + (tx - 1) * d;
            if (sx < 0 || sx >= 128) continue;
            uint4 raw = *(const uint4*)(dxb + (size_t)((n << 14) + sy * 128 + sx) * 128 + i * 8);
            float a[8];
            bfpair(raw.x, a[0], a[1]); bfpair(raw.y, a[2], a[3]);
            bfpair(raw.z, a[4], a[5]); bfpair(raw.w, a[6], a[7]);
            int wb = (ty * 3 + tx) * 64;
            #pragma unroll
            for (int ci = 0; ci < 8; ci++) {
                float xv = a[ci];
                float4 k0 = *(const float4*)&wk[wb + ci * 8];
                float4 k1 = *(const float4*)&wk[wb + ci * 8 + 4];
                float4 q0 = *(const float4*)&wq[wb + ci * 8];
                float4 q1 = *(const float4*)&wq[wb + ci * 8 + 4];
                float4 v0 = *(const float4*)&wv_[wb + ci * 8];
                float4 v1 = *(const float4*)&wv_[wb + ci * 8 + 4];
                k[0] = fmaf(xv, k0.x, k[0]); k[1] = fmaf(xv, k0.y, k[1]);
                k[2] = fmaf(xv, k0.z, k[2]); k[3] = fmaf(xv, k0.w, k[3]);
                k[4] = fmaf(xv, k1.x, k[4]); k[5] = fmaf(xv, k1.y, k[5]);
                k[6] = fmaf(xv, k1.z, k[6]); k[7] = fmaf(xv, k1.w, k[7]);
                q[0] = fmaf(xv, q0.x, q[0]); q[1] = fmaf(xv, q0.y, q[1]);
                q[2] = fmaf(xv, q0.z, q[2]); q[3] = fmaf(xv, q0.w, q[3]);
                q[4] = fmaf(xv, q1.x, q[4]); q[5] = fmaf(xv, q1.y, q[5]);
                q[6] = fmaf(xv, q1.z, q[6]); q[7] = fmaf(xv, q1.w, q[7]);
                v[0] = fmaf(xv, v0.x, v[0]); v[1] = fmaf(xv, v0.y, v[1]);
                v[2] = fmaf(xv, v0.z, v[2]); v[3] = fmaf(xv, v0.w, v[3]);
                v[4] = fmaf(xv, v1.x, v[4]); v[5] = fmaf(xv, v1.y, v[5]);
                v[6] = fmaf(xv, v1.z, v[6]); v[7] = fmaf(xv, v1.w, v[7]);
            }
        }
    }
    #pragma unroll
    for (int f = 0; f < 8; f++) {
        float kk = fmaxf(k[f], 0.f), qq = fmaxf(q[f], 0.f);
        kq_t[((size_t)(n * 128 + i * 8 + f) << 14) + hw] = kk * qq;
    }
    float4* vp = (float4*)(vbuf + (size_t)pix * 128 + i * 8);
    vp[0] = make_float4(fmaxf(v[0], 0.f), fmaxf(v[1], 0.f), fmaxf(v[2], 0.f), fmaxf(v[3], 0.f));
    vp[1] = make_float4(fmaxf(v[4], 0.f), fmaxf(v[5], 0.f), fmaxf(v[6], 0.f), fmaxf(v[7], 0.f));
}

// -------- K4: spatial softmax stats per (n, branch-chan) ---------------------------
__global__ void softmax_stats_kernel(const float* __restrict__ kq_t, float2* __restrict__ stats) {
    int r = blockIdx.x;
    const float* base = kq_t + ((size_t)r << 14);
    int tid = threadIdx.x;
    int wid = tid >> 6, lane = tid & 63;
    __shared__ float red[4], red2[4];
    float m = -1e30f;
    for (int idx = tid; idx < HW; idx += 256) m = fmaxf(m, base[idx]);
    #pragma unroll
    for (int msk = 1; msk < 64; msk <<= 1) m = fmaxf(m, __shfl_xor(m, msk));
    if (lane == 0) red[wid] = m;
    __syncthreads();
    m = fmaxf(fmaxf(red[0], red[1]), fmaxf(red[2], red[3]));
    float s = 0.f;
    for (int idx = tid; idx < HW; idx += 256) s += __expf(base[idx] - m);
    #pragma unroll
    for (int msk = 1; msk < 64; msk <<= 1) s += __shfl_xor(s, msk);
    if (lane == 0) red2[wid] = s;
    __syncthreads();
    if (tid == 0) stats[r] = make_float2(m, red2[0] + red2[1] + red2[2] + red2[3]);
}

// -------- K5: attn*v + LN(8) -> cat[:,256:384] bf16 --------------------------------
__global__ void branch_out_kernel(const float* __restrict__ kq_t, const float* __restrict__ vbuf,
                                  const float2* __restrict__ stats,
                                  const float* __restrict__ g_up, const float* __restrict__ b_up,
                                  unsigned short* __restrict__ cat) {
    int i = blockIdx.y;
    int pix = blockIdx.x * 256 + threadIdx.x;
    int n = pix >> 14, hw = pix & 16383;
    float va[8];
    *(float4*)&va[0] = *(const float4*)(vbuf + (size_t)pix * 128 + i * 8);
    *(float4*)&va[4] = *(const float4*)(vbuf + (size_t)pix * 128 + i * 8 + 4);
    float y[8];
    float s = 0.f, ss = 0.f;
    #pragma unroll
    for (int f = 0; f < 8; f++) {
        int r = n * 128 + i * 8 + f;
        float2 st = stats[r];
        float a = __expf(kq_t[((size_t)r << 14) + hw] - st.x) / st.y;
        y[f] = a * va[f];
        s += y[f]; ss += y[f] * y[f];
    }
    float m = s * 0.125f;
    float rstd = rsqrtf(ss * 0.125f - m * m + LNEPS);
    unsigned short o[8];
    #pragma unroll
    for (int f = 0; f < 8; f++) o[f] = f2bf((y[f] - m) * rstd * g_up[f] + b_up[f]);
    ushort4* cp = (ushort4*)(cat + (size_t)pix * CATC + 256 + i * 8);
    cp[0] = make_ushort4(o[0], o[1], o[2], o[3]);
    cp[1] = make_ushort4(o[4], o[5], o[6], o[7]);
}

// -------- K6: smooth 3x3 conv (384->256), M=128 row, neighborhood LDS, B via L2 -----
__global__ __launch_bounds__(256, 2)
void smooth_ln_kernel(const unsigned short* __restrict__ cat, const unsigned short* __restrict__ Wbf,
                      const float* __restrict__ smooth_b, const float* __restrict__ g_out,
                      const float* __restrict__ b_out, float* __restrict__ out) {
    __shared__ unsigned short Alds[3 * 130 * 40];   // 3 rows x 130 halo-cols x 32ch (pad 40)
    __shared__ float pwave[4][128][2];
    __shared__ float mrs[128][2];
    int tid = threadIdx.x;
    int wv = tid >> 6, lane = tid & 63;
    int ml = lane & 15, quad = lane >> 4;
    int rowid = blockIdx.x;                  // 0..511 : (n,h)
    int n = rowid >> 7, h0 = rowid & 127;
    int pb = rowid * 128;                    // first pixel of this row

    float sbias[4], gg[4], bb[4];
    #pragma unroll
    for (int ni = 0; ni < 4; ni++) {
        int co = wv * 64 + ni * 16 + ml;
        sbias[ni] = smooth_b[co]; gg[ni] = g_out[co]; bb[ni] = b_out[co];
    }
    f32x4 acc[8][4];
    #pragma unroll
    for (int mi = 0; mi < 8; mi++)
        #pragma unroll
        for (int ni = 0; ni < 4; ni++) acc[mi][ni] = (f32x4){0.f, 0.f, 0.f, 0.f};

    for (int kc = 0; kc < 12; kc++) {
        __syncthreads();
        // stage 3x130 neighborhood, 32 channels
        for (int it = 0; it < 7; it++) {
            int idx = it * 256 + tid;
            if (idx < 1560) {
                int r3 = (idx >= 1040) ? 2 : ((idx >= 520) ? 1 : 0);
                int rem = idx - r3 * 520;
                int c130 = rem >> 2, sub = rem & 3;
                int srow = h0 + r3 - 1, scol = c130 - 1;
                uint4 av = make_uint4(0u, 0u, 0u, 0u);
                if ((unsigned)srow < 128u && (unsigned)scol < 128u)
                    av = *(const uint4*)(cat + (size_t)((n << 14) + srow * 128 + scol) * CATC + kc * 32 + sub * 8);
                *(uint4*)&Alds[(r3 * 130 + c130) * 40 + sub * 8] = av;
            }
        }
        __syncthreads();
        #pragma unroll
        for (int tap = 0; tap < 9; tap++) {
            const int dy = tap / 3, dxo = tap % 3;
            bf16x8 bv[4];
            #pragma unroll
            for (int ni = 0; ni < 4; ni++)
                bv[ni] = *(const bf16x8*)(Wbf + ((size_t)((kc * 9 + tap) * 256 + wv * 64 + ni * 16 + ml)) * 32 + quad * 8);
            bf16x8 af[8];
            #pragma unroll
            for (int mi = 0; mi < 8; mi++)
                af[mi] = *(const bf16x8*)&Alds[(dy * 130 + mi * 16 + ml + dxo) * 40 + quad * 8];
            #pragma unroll
            for (int mi = 0; mi < 8; mi++)
                #pragma unroll
                for (int ni = 0; ni < 4; ni++)
                    acc[mi][ni] = __builtin_amdgcn_mfma_f32_16x16x32_bf16(af[mi], bv[ni], acc[mi][ni], 0, 0, 0);
        }
    }
    // fused bias + relu + LN(256) epilogue
    #pragma unroll
    for (int mi = 0; mi < 8; mi++) {
        #pragma unroll
        for (int rg = 0; rg < 4; rg++) {
            float s = 0.f, ss = 0.f;
            #pragma unroll
            for (int ni = 0; ni < 4; ni++) {
                float v = fmaxf(acc[mi][ni][rg] + sbias[ni], 0.f);
                s += v; ss += v * v;
            }
            #pragma unroll
            for (int msk = 1; msk < 16; msk <<= 1) { s += __shfl_xor(s, msk); ss += __shfl_xor(ss, msk); }
            if (ml == 0) {
                int P = mi * 16 + quad * 4 + rg;
                pwave[wv][P][0] = s; pwave[wv][P][1] = ss;
            }
        }
    }
    __syncthreads();
    if (tid < 128) {
        float s = pwave[0][tid][0] + pwave[1][tid][0] + pwave[2][tid][0] + pwave[3][tid][0];
        float ss = pwave[0][tid][1] + pwave[1][tid][1] + pwave[2][tid][1] + pwave[3][tid][1];
        float m = s * (1.f / 256.f);
        mrs[tid][0] = m;
        mrs[tid][1] = rsqrtf(ss * (1.f / 256.f) - m * m + LNEPS);
    }
    __syncthreads();
    #pragma unroll
    for (int mi = 0; mi < 8; mi++) {
        #pragma unroll
        for (int rg = 0; rg < 4; rg++) {
            int P = mi * 16 + quad * 4 + rg;
            float m = mrs[P][0], rs = mrs[P][1];
            #pragma unroll
            for (int ni = 0; ni < 4; ni++) {
                float v = fmaxf(acc[mi][ni][rg] + sbias[ni], 0.f);
                out[(size_t)(pb + P) * 256 + wv * 64 + ni * 16 + ml] = (v - m) * rs * gg[ni] + bb[ni];
            }
        }
    }
}

extern "C" void kernel_launch(void* const* d_in, const int* in_sizes, int n_in,
                              void* d_out, int out_size, void* d_ws, size_t ws_size,
                              hipStream_t stream) {
    const float* x        = (const float*)d_in[0];
    const float* dwn_w    = (const float*)d_in[1];
    const float* dwn_b    = (const float*)d_in[2];
    const float* k_w      = (const float*)d_in[3];
    const float* k_b      = (const float*)d_in[4];
    const float* q_w      = (const float*)d_in[5];
    const float* q_b      = (const float*)d_in[6];
    const float* v_w      = (const float*)d_in[7];
    const float* v_b      = (const float*)d_in[8];
    const float* smooth_w = (const float*)d_in[9];
    const float* smooth_b = (const float*)d_in[10];
    const float* ln_in_g  = (const float*)d_in[11];
    const float* ln_in_b  = (const float*)d_in[12];
    const float* ln_up_g  = (const float*)d_in[13];
    const float* ln_up_b  = (const float*)d_in[14];
    const float* ln_out_g = (const float*)d_in[15];
    const float* ln_out_b = (const float*)d_in[16];

    char* ws = (char*)d_ws;
    unsigned short* dxb   = (unsigned short*)(ws);                 // 16 MB
    float*          kq_t  = (float*)(ws + 16777216);               // 32 MB
    float*          vbuf  = (float*)(ws + 50331648);               // 32 MB
    unsigned short* cat   = (unsigned short*)(ws + 83886080);      // 48 MB
    float2*         stats = (float2*)(ws + 134217728);             // 4 KB
    unsigned short* Wd    = (unsigned short*)(ws + 134221824);     // 64 KB
    unsigned short* Wbf   = (unsigned short*)(ws + 134287360);     // 1.7 MB
    float* out = (float*)d_out;

    prep_kernel<<<3584, 256, 0, stream>>>(dwn_w, smooth_w, Wd, Wbf);
    ln_in_kernel<<<16384, 256, 0, stream>>>(x, ln_in_g, ln_in_b, cat);
    dwn_mfma_kernel<<<512, 256, 0, stream>>>(cat, Wd, dwn_b, dxb);
    branch_conv_kernel<<<dim3(256, 16), 256, 0, stream>>>(dxb, k_w, k_b, q_w, q_b, v_w, v_b, kq_t, vbuf);
    softmax_stats_kernel<<<512, 256, 0, stream>>>(kq_t, stats);
    branch_out_kernel<<<dim3(256, 16), 256, 0, stream>>>(kq_t, vbuf, stats, ln_up_g, ln_up_b, cat);
    smooth_ln_kernel<<<512, 256, 0, stream>>>(cat, Wbf, smooth_b, ln_out_g, ln_out_b, out);
}

// Round 3
// 381.756 us; speedup vs baseline: 1.4987x; 1.0883x over previous
//
#include <hip/hip_runtime.h>
#include <hip/hip_bf16.h>

#define HW 16384
#define NPIX 65536
#define CC 256
#define NDIL 16
#define DFF 8
#define CATC 384
#define LNEPS 1e-3f

typedef short bf16x8 __attribute__((ext_vector_type(8)));
typedef float f32x4 __attribute__((ext_vector_type(4)));

__device__ __forceinline__ unsigned short f2bf(float f) {
    unsigned u = __builtin_bit_cast(unsigned, f);
    u += 0x7fffu + ((u >> 16) & 1u);
    return (unsigned short)(u >> 16);
}
__device__ __forceinline__ void bfpair(unsigned u, float& a, float& b) {
    a = __builtin_bit_cast(float, u << 16);
    b = __builtin_bit_cast(float, u & 0xffff0000u);
}

// -------- prep: dwn weights -> bf16 [co=128][k=256]; smooth -> bf16 [kc][tap][co][32]
__global__ void prep_kernel(const float* __restrict__ dwn_w,
                            const float* __restrict__ smooth_w,
                            unsigned short* __restrict__ Wd, unsigned short* __restrict__ Wbf) {
    int idx = blockIdx.x * 256 + threadIdx.x;
    if (idx < 128 * 256) {
        int co = idx >> 8, k = idx & 255;
        int i = co >> 3, f = co & 7;
        Wd[idx] = f2bf(dwn_w[(i * 256 + k) * 8 + f]);     // dwn_w [ND][1][1][C][DF]
    }
    int idx2 = idx - 128 * 256;
    if (idx2 >= 0 && idx2 < 12 * 9 * 256 * 32) {
        int k = idx2 & 31;
        int t = idx2 >> 5;
        int co = t & 255;
        int t2 = t >> 8;
        int tap = t2 % 9;
        int kc = t2 / 9;
        int ci = kc * 32 + k;
        Wbf[idx2] = f2bf(smooth_w[(tap * 384 + ci) * 256 + co]); // smooth_w [3][3][CAT][C]
    }
}

// -------- K1: input LN -> bf16 cat[:,0:256] ----------------------------------------
__global__ void ln_in_kernel(const float* __restrict__ x, const float* __restrict__ g,
                             const float* __restrict__ b, unsigned short* __restrict__ cat) {
    int wid = threadIdx.x >> 6, lane = threadIdx.x & 63;
    int pix = blockIdx.x * 4 + wid;
    float4 v = ((const float4*)(x + (size_t)pix * CC))[lane];
    float s = v.x + v.y + v.z + v.w;
    float ss = v.x * v.x + v.y * v.y + v.z * v.z + v.w * v.w;
    #pragma unroll
    for (int m = 1; m < 64; m <<= 1) { s += __shfl_xor(s, m); ss += __shfl_xor(ss, m); }
    float mean = s * (1.f / 256.f);
    float rstd = rsqrtf(ss * (1.f / 256.f) - mean * mean + LNEPS);
    float4 gv = ((const float4*)g)[lane];
    float4 bv = ((const float4*)b)[lane];
    float4 y;
    y.x = (v.x - mean) * rstd * gv.x + bv.x;
    y.y = (v.y - mean) * rstd * gv.y + bv.y;
    y.z = (v.z - mean) * rstd * gv.z + bv.z;
    y.w = (v.w - mean) * rstd * gv.w + bv.w;
    ushort4* cp = (ushort4*)(cat + (size_t)pix * CATC + lane * 4);
    *cp = make_ushort4(f2bf(y.x), f2bf(y.y), f2bf(y.z), f2bf(y.w));
}

// -------- K2: dwn 1x1 conv as bf16 MFMA GEMM (65536 x 256 x 128), relu, bf16 out ----
__global__ __launch_bounds__(256)
void dwn_mfma_kernel(const unsigned short* __restrict__ cat, const unsigned short* __restrict__ Wd,
                     const float* __restrict__ dwn_b, unsigned short* __restrict__ dxb) {
    __shared__ unsigned short Alds[128 * 40];
    int tid = threadIdx.x;
    int wv = tid >> 6, lane = tid & 63;
    int ml = lane & 15, quad = lane >> 4;
    int pb = blockIdx.x * 128;
    f32x4 acc[8][2];
    #pragma unroll
    for (int mi = 0; mi < 8; mi++)
        #pragma unroll
        for (int ni = 0; ni < 2; ni++) acc[mi][ni] = (f32x4){0.f, 0.f, 0.f, 0.f};

    for (int kc = 0; kc < 8; kc++) {
        __syncthreads();
        #pragma unroll
        for (int it = 0; it < 2; it++) {
            int idx = it * 256 + tid;
            int p = idx >> 2, sub = idx & 3;
            uint4 av = *(const uint4*)(cat + (size_t)(pb + p) * CATC + kc * 32 + sub * 8);
            *(uint4*)&Alds[p * 40 + sub * 8] = av;
        }
        __syncthreads();
        bf16x8 bv[2];
        #pragma unroll
        for (int ni = 0; ni < 2; ni++) {
            int co = wv * 32 + ni * 16 + ml;
            bv[ni] = *(const bf16x8*)(Wd + (size_t)co * 256 + kc * 32 + quad * 8);
        }
        bf16x8 af[8];
        #pragma unroll
        for (int mi = 0; mi < 8; mi++)
            af[mi] = *(const bf16x8*)&Alds[(mi * 16 + ml) * 40 + quad * 8];
        #pragma unroll
        for (int mi = 0; mi < 8; mi++)
            #pragma unroll
            for (int ni = 0; ni < 2; ni++)
                acc[mi][ni] = __builtin_amdgcn_mfma_f32_16x16x32_bf16(af[mi], bv[ni], acc[mi][ni], 0, 0, 0);
    }
    float bias[2];
    #pragma unroll
    for (int ni = 0; ni < 2; ni++) bias[ni] = dwn_b[wv * 32 + ni * 16 + ml];
    #pragma unroll
    for (int mi = 0; mi < 8; mi++)
        #pragma unroll
        for (int rg = 0; rg < 4; rg++) {
            int pixel = mi * 16 + quad * 4 + rg;
            #pragma unroll
            for (int ni = 0; ni < 2; ni++) {
                float v = fmaxf(acc[mi][ni][rg] + bias[ni], 0.f);
                dxb[(size_t)(pb + pixel) * 128 + wv * 32 + ni * 16 + ml] = f2bf(v);
            }
        }
}

// -------- K3: per-branch dilated 3x3 k,q,v convs; 4 px/thread, zero-pad via select --
__global__ __launch_bounds__(256)
void branch_conv_kernel(const unsigned short* __restrict__ dxb,
                        const float* __restrict__ k_w, const float* __restrict__ k_b,
                        const float* __restrict__ q_w, const float* __restrict__ q_b,
                        const float* __restrict__ v_w, const float* __restrict__ v_b,
                        float* __restrict__ kq_t, float* __restrict__ vbuf) {
    __shared__ float wk[576], wq[576], wv_[576];
    __shared__ float bk[8], bq[8], bv[8];
    int i = blockIdx.y;
    int tid = threadIdx.x;
    for (int idx = tid; idx < 576; idx += 256) {
        wk[idx] = k_w[i * 576 + idx];
        wq[idx] = q_w[i * 576 + idx];
        wv_[idx] = v_w[i * 576 + idx];
    }
    if (tid < 8) { bk[tid] = k_b[i * 8 + tid]; bq[tid] = q_b[i * 8 + tid]; bv[tid] = v_b[i * 8 + tid]; }
    __syncthreads();

    int pix0 = blockIdx.x * 1024 + tid;     // 4 pixels: pix0 + g*256, all same image
    int n = pix0 >> 14;
    int w = pix0 & 127;
    int d = i + 1;
    int h[4];
    #pragma unroll
    for (int g = 0; g < 4; g++) h[g] = ((pix0 + g * 256) & 16383) >> 7;

    float k[4][8], q[4][8], v[4][8];
    #pragma unroll
    for (int g = 0; g < 4; g++)
        #pragma unroll
        for (int f = 0; f < 8; f++) { k[g][f] = bk[f]; q[g][f] = bq[f]; v[g][f] = bv[f]; }

    const unsigned short* dbase = dxb + ((size_t)n << 14) * 128 + i * 8;

    for (int ty = 0; ty < 3; ty++) {
        for (int tx = 0; tx < 3; tx++) {
            int sxo = w + (tx - 1) * d;
            bool okx = (unsigned)sxo < 128u;
            float a[4][8];
            #pragma unroll
            for (int g = 0; g < 4; g++) {
                int sy = h[g] + (ty - 1) * d;
                bool ok = okx && ((unsigned)sy < 128u);
                int off = ok ? (sy * 128 + sxo) : 0;
                uint4 raw = *(const uint4*)(dbase + (size_t)off * 128);
                if (!ok) raw = make_uint4(0u, 0u, 0u, 0u);
                bfpair(raw.x, a[g][0], a[g][1]); bfpair(raw.y, a[g][2], a[g][3]);
                bfpair(raw.z, a[g][4], a[g][5]); bfpair(raw.w, a[g][6], a[g][7]);
            }
            int wb = (ty * 3 + tx) * 64;
            #pragma unroll
            for (int ci = 0; ci < 8; ci++) {
                float4 k0 = *(const float4*)&wk[wb + ci * 8];
                float4 k1 = *(const float4*)&wk[wb + ci * 8 + 4];
                float4 q0 = *(const float4*)&wq[wb + ci * 8];
                float4 q1 = *(const float4*)&wq[wb + ci * 8 + 4];
                float4 v0 = *(const float4*)&wv_[wb + ci * 8];
                float4 v1 = *(const float4*)&wv_[wb + ci * 8 + 4];
                #pragma unroll
                for (int g = 0; g < 4; g++) {
                    float xv = a[g][ci];
                    k[g][0] = fmaf(xv, k0.x, k[g][0]); k[g][1] = fmaf(xv, k0.y, k[g][1]);
                    k[g][2] = fmaf(xv, k0.z, k[g][2]); k[g][3] = fmaf(xv, k0.w, k[g][3]);
                    k[g][4] = fmaf(xv, k1.x, k[g][4]); k[g][5] = fmaf(xv, k1.y, k[g][5]);
                    k[g][6] = fmaf(xv, k1.z, k[g][6]); k[g][7] = fmaf(xv, k1.w, k[g][7]);
                    q[g][0] = fmaf(xv, q0.x, q[g][0]); q[g][1] = fmaf(xv, q0.y, q[g][1]);
                    q[g][2] = fmaf(xv, q0.z, q[g][2]); q[g][3] = fmaf(xv, q0.w, q[g][3]);
                    q[g][4] = fmaf(xv, q1.x, q[g][4]); q[g][5] = fmaf(xv, q1.y, q[g][5]);
                    q[g][6] = fmaf(xv, q1.z, q[g][6]); q[g][7] = fmaf(xv, q1.w, q[g][7]);
                    v[g][0] = fmaf(xv, v0.x, v[g][0]); v[g][1] = fmaf(xv, v0.y, v[g][1]);
                    v[g][2] = fmaf(xv, v0.z, v[g][2]); v[g][3] = fmaf(xv, v0.w, v[g][3]);
                    v[g][4] = fmaf(xv, v1.x, v[g][4]); v[g][5] = fmaf(xv, v1.y, v[g][5]);
                    v[g][6] = fmaf(xv, v1.z, v[g][6]); v[g][7] = fmaf(xv, v1.w, v[g][7]);
                }
            }
        }
    }
    #pragma unroll
    for (int g = 0; g < 4; g++) {
        int pix = pix0 + g * 256;
        int hw = pix & 16383;
        #pragma unroll
        for (int f = 0; f < 8; f++) {
            float kk = fmaxf(k[g][f], 0.f), qq = fmaxf(q[g][f], 0.f);
            kq_t[((size_t)(n * 128 + i * 8 + f) << 14) + hw] = kk * qq;
        }
        float4* vp = (float4*)(vbuf + (size_t)pix * 128 + i * 8);
        vp[0] = make_float4(fmaxf(v[g][0], 0.f), fmaxf(v[g][1], 0.f), fmaxf(v[g][2], 0.f), fmaxf(v[g][3], 0.f));
        vp[1] = make_float4(fmaxf(v[g][4], 0.f), fmaxf(v[g][5], 0.f), fmaxf(v[g][6], 0.f), fmaxf(v[g][7], 0.f));
    }
}

// -------- K4: online softmax stats per (n, branch-chan), single pass ---------------
__global__ void softmax_stats_kernel(const float* __restrict__ kq_t, float2* __restrict__ stats) {
    int r = blockIdx.x;
    const float4* base = (const float4*)(kq_t + ((size_t)r << 14));
    int tid = threadIdx.x;
    float m = -1e30f, s = 0.f;
    for (int it = 0; it < 16; it++) {
        float4 v = base[it * 256 + tid];
        float mx = fmaxf(fmaxf(v.x, v.y), fmaxf(v.z, v.w));
        if (mx > m) { s *= __expf(m - mx); m = mx; }
        s += __expf(v.x - m) + __expf(v.y - m) + __expf(v.z - m) + __expf(v.w - m);
    }
    #pragma unroll
    for (int msk = 1; msk < 64; msk <<= 1) {
        float m2 = __shfl_xor(m, msk), s2 = __shfl_xor(s, msk);
        float M = fmaxf(m, m2);
        s = s * __expf(m - M) + s2 * __expf(m2 - M);
        m = M;
    }
    __shared__ float rm[4], rs[4];
    int wid = tid >> 6, lane = tid & 63;
    if (lane == 0) { rm[wid] = m; rs[wid] = s; }
    __syncthreads();
    if (tid == 0) {
        float M = fmaxf(fmaxf(rm[0], rm[1]), fmaxf(rm[2], rm[3]));
        float S = rs[0] * __expf(rm[0] - M) + rs[1] * __expf(rm[1] - M)
                + rs[2] * __expf(rm[2] - M) + rs[3] * __expf(rm[3] - M);
        stats[r] = make_float2(M, S);
    }
}

// -------- K5: attn*v + LN(8) -> cat[:,256:384] bf16 --------------------------------
__global__ void branch_out_kernel(const float* __restrict__ kq_t, const float* __restrict__ vbuf,
                                  const float2* __restrict__ stats,
                                  const float* __restrict__ g_up, const float* __restrict__ b_up,
                                  unsigned short* __restrict__ cat) {
    int i = blockIdx.y;
    int pix = blockIdx.x * 256 + threadIdx.x;
    int n = pix >> 14, hw = pix & 16383;
    float va[8];
    *(float4*)&va[0] = *(const float4*)(vbuf + (size_t)pix * 128 + i * 8);
    *(float4*)&va[4] = *(const float4*)(vbuf + (size_t)pix * 128 + i * 8 + 4);
    float y[8];
    float s = 0.f, ss = 0.f;
    #pragma unroll
    for (int f = 0; f < 8; f++) {
        int r = n * 128 + i * 8 + f;
        float2 st = stats[r];
        float a = __expf(kq_t[((size_t)r << 14) + hw] - st.x) / st.y;
        y[f] = a * va[f];
        s += y[f]; ss += y[f] * y[f];
    }
    float m = s * 0.125f;
    float rstd = rsqrtf(ss * 0.125f - m * m + LNEPS);
    unsigned short o[8];
    #pragma unroll
    for (int f = 0; f < 8; f++) o[f] = f2bf((y[f] - m) * rstd * g_up[f] + b_up[f]);
    ushort4* cp = (ushort4*)(cat + (size_t)pix * CATC + 256 + i * 8);
    cp[0] = make_ushort4(o[0], o[1], o[2], o[3]);
    cp[1] = make_ushort4(o[4], o[5], o[6], o[7]);
}

// -------- K6: smooth 3x3 conv (384->256), M=128 row, neighborhood LDS, B via L2 -----
__global__ __launch_bounds__(256, 2)
void smooth_ln_kernel(const unsigned short* __restrict__ cat, const unsigned short* __restrict__ Wbf,
                      const float* __restrict__ smooth_b, const float* __restrict__ g_out,
                      const float* __restrict__ b_out, float* __restrict__ out) {
    __shared__ unsigned short Alds[3 * 130 * 40];   // 3 rows x 130 halo-cols x 32ch (pad 40)
    __shared__ float pwave[4][128][2];
    __shared__ float mrs[128][2];
    int tid = threadIdx.x;
    int wv = tid >> 6, lane = tid & 63;
    int ml = lane & 15, quad = lane >> 4;
    int rowid = blockIdx.x;                  // 0..511 : (n,h)
    int n = rowid >> 7, h0 = rowid & 127;
    int pb = rowid * 128;                    // first pixel of this row

    float sbias[4], gg[4], bb[4];
    #pragma unroll
    for (int ni = 0; ni < 4; ni++) {
        int co = wv * 64 + ni * 16 + ml;
        sbias[ni] = smooth_b[co]; gg[ni] = g_out[co]; bb[ni] = b_out[co];
    }
    f32x4 acc[8][4];
    #pragma unroll
    for (int mi = 0; mi < 8; mi++)
        #pragma unroll
        for (int ni = 0; ni < 4; ni++) acc[mi][ni] = (f32x4){0.f, 0.f, 0.f, 0.f};

    for (int kc = 0; kc < 12; kc++) {
        __syncthreads();
        // stage 3x130 neighborhood, 32 channels
        for (int it = 0; it < 7; it++) {
            int idx = it * 256 + tid;
            if (idx < 1560) {
                int r3 = (idx >= 1040) ? 2 : ((idx >= 520) ? 1 : 0);
                int rem = idx - r3 * 520;
                int c130 = rem >> 2, sub = rem & 3;
                int srow = h0 + r3 - 1, scol = c130 - 1;
                uint4 av = make_uint4(0u, 0u, 0u, 0u);
                if ((unsigned)srow < 128u && (unsigned)scol < 128u)
                    av = *(const uint4*)(cat + (size_t)((n << 14) + srow * 128 + scol) * CATC + kc * 32 + sub * 8);
                *(uint4*)&Alds[(r3 * 130 + c130) * 40 + sub * 8] = av;
            }
        }
        __syncthreads();
        #pragma unroll
        for (int tap = 0; tap < 9; tap++) {
            const int dy = tap / 3, dxo = tap % 3;
            bf16x8 bv[4];
            #pragma unroll
            for (int ni = 0; ni < 4; ni++)
                bv[ni] = *(const bf16x8*)(Wbf + ((size_t)((kc * 9 + tap) * 256 + wv * 64 + ni * 16 + ml)) * 32 + quad * 8);
            bf16x8 af[8];
            #pragma unroll
            for (int mi = 0; mi < 8; mi++)
                af[mi] = *(const bf16x8*)&Alds[(dy * 130 + mi * 16 + ml + dxo) * 40 + quad * 8];
            #pragma unroll
            for (int mi = 0; mi < 8; mi++)
                #pragma unroll
                for (int ni = 0; ni < 4; ni++)
                    acc[mi][ni] = __builtin_amdgcn_mfma_f32_16x16x32_bf16(af[mi], bv[ni], acc[mi][ni], 0, 0, 0);
        }
    }
    // fused bias + relu + LN(256) epilogue
    #pragma unroll
    for (int mi = 0; mi < 8; mi++) {
        #pragma unroll
        for (int rg = 0; rg < 4; rg++) {
            float s = 0.f, ss = 0.f;
            #pragma unroll
            for (int ni = 0; ni < 4; ni++) {
                float v = fmaxf(acc[mi][ni][rg] + sbias[ni], 0.f);
                s += v; ss += v * v;
            }
            #pragma unroll
            for (int msk = 1; msk < 16; msk <<= 1) { s += __shfl_xor(s, msk); ss += __shfl_xor(ss, msk); }
            if (ml == 0) {
                int P = mi * 16 + quad * 4 + rg;
                pwave[wv][P][0] = s; pwave[wv][P][1] = ss;
            }
        }
    }
    __syncthreads();
    if (tid < 128) {
        float s = pwave[0][tid][0] + pwave[1][tid][0] + pwave[2][tid][0] + pwave[3][tid][0];
        float ss = pwave[0][tid][1] + pwave[1][tid][1] + pwave[2][tid][1] + pwave[3][tid][1];
        float m = s * (1.f / 256.f);
        mrs[tid][0] = m;
        mrs[tid][1] = rsqrtf(ss * (1.f / 256.f) - m * m + LNEPS);
    }
    __syncthreads();
    #pragma unroll
    for (int mi = 0; mi < 8; mi++) {
        #pragma unroll
        for (int rg = 0; rg < 4; rg++) {
            int P = mi * 16 + quad * 4 + rg;
            float m = mrs[P][0], rs = mrs[P][1];
            #pragma unroll
            for (int ni = 0; ni < 4; ni++) {
                float v = fmaxf(acc[mi][ni][rg] + sbias[ni], 0.f);
                out[(size_t)(pb + P) * 256 + wv * 64 + ni * 16 + ml] = (v - m) * rs * gg[ni] + bb[ni];
            }
        }
    }
}

extern "C" void kernel_launch(void* const* d_in, const int* in_sizes, int n_in,
                              void* d_out, int out_size, void* d_ws, size_t ws_size,
                              hipStream_t stream) {
    const float* x        = (const float*)d_in[0];
    const float* dwn_w    = (const float*)d_in[1];
    const float* dwn_b    = (const float*)d_in[2];
    const float* k_w      = (const float*)d_in[3];
    const float* k_b      = (const float*)d_in[4];
    const float* q_w      = (const float*)d_in[5];
    const float* q_b      = (const float*)d_in[6];
    const float* v_w      = (const float*)d_in[7];
    const float* v_b      = (const float*)d_in[8];
    const float* smooth_w = (const float*)d_in[9];
    const float* smooth_b = (const float*)d_in[10];
    const float* ln_in_g  = (const float*)d_in[11];
    const float* ln_in_b  = (const float*)d_in[12];
    const float* ln_up_g  = (const float*)d_in[13];
    const float* ln_up_b  = (const float*)d_in[14];
    const float* ln_out_g = (const float*)d_in[15];
    const float* ln_out_b = (const float*)d_in[16];

    char* ws = (char*)d_ws;
    unsigned short* dxb   = (unsigned short*)(ws);                 // 16 MB
    float*          kq_t  = (float*)(ws + 16777216);               // 32 MB
    float*          vbuf  = (float*)(ws + 50331648);               // 32 MB
    unsigned short* cat   = (unsigned short*)(ws + 83886080);      // 48 MB
    float2*         stats = (float2*)(ws + 134217728);             // 4 KB
    unsigned short* Wd    = (unsigned short*)(ws + 134221824);     // 64 KB
    unsigned short* Wbf   = (unsigned short*)(ws + 134287360);     // 1.7 MB
    float* out = (float*)d_out;

    prep_kernel<<<3584, 256, 0, stream>>>(dwn_w, smooth_w, Wd, Wbf);
    ln_in_kernel<<<16384, 256, 0, stream>>>(x, ln_in_g, ln_in_b, cat);
    dwn_mfma_kernel<<<512, 256, 0, stream>>>(cat, Wd, dwn_b, dxb);
    branch_conv_kernel<<<dim3(64, 16), 256, 0, stream>>>(dxb, k_w, k_b, q_w, q_b, v_w, v_b, kq_t, vbuf);
    softmax_stats_kernel<<<512, 256, 0, stream>>>(kq_t, stats);
    branch_out_kernel<<<dim3(256, 16), 256, 0, stream>>>(kq_t, vbuf, stats, ln_up_g, ln_up_b, cat);
    smooth_ln_kernel<<<512, 256, 0, stream>>>(cat, Wbf, smooth_b, ln_out_g, ln_out_b, out);
}